// Round 2
// baseline (1000.211 us; speedup 1.0000x reference)
//
#include <hip/hip_runtime.h>

#define S_SEG 2048
#define C_ALL 64
#define P_PIX (1024 * 1024)
#define CH_PER 4        // channels per block
#define N_GROUPS 16     // 16 * 4 = 64 channels
#define N_CHUNKS 64     // pixel chunks
#define BLOCK 512
#define PIX_PER_BLOCK (P_PIX / N_CHUNKS)  // 16384

// ws layout (floats):
//   sum_g : [64][2048]  at 0        (131072)
//   sq_g  : [2048]      at 131072
//   cnt_g : [2048]      at 133120
//   accum : [2]         at 135168   (var_loss_sum, c_count)
#define OFF_SQ   131072
#define OFF_CNT  133120
#define OFF_ACC  135168
#define N_ZERO   135170

__global__ void zero_kernel(float* __restrict__ p, int n) {
    int i = blockIdx.x * blockDim.x + threadIdx.x;
    if (i < n) p[i] = 0.0f;
}

// counts: trivial histogram of sp[0] (1M lane-atomics total)
__global__ __launch_bounds__(256) void count_kernel(const int* __restrict__ sp,
                                                    float* __restrict__ cnt_g) {
    __shared__ float cnt_h[S_SEG];
    const int tid = threadIdx.x;
    for (int i = tid; i < S_SEG; i += 256) cnt_h[i] = 0.0f;
    __syncthreads();
    const int base = blockIdx.x * (P_PIX / 32);  // 32 blocks
    const int4* sp4 = (const int4*)(sp + base);
    const int iters = (P_PIX / 32) / (256 * 4);  // 32
    for (int it = 0; it < iters; ++it) {
        const int4 s4 = sp4[it * 256 + tid];
        atomicAdd(&cnt_h[s4.x], 1.0f);
        atomicAdd(&cnt_h[s4.y], 1.0f);
        atomicAdd(&cnt_h[s4.z], 1.0f);
        atomicAdd(&cnt_h[s4.w], 1.0f);
    }
    __syncthreads();
    for (int i = tid; i < S_SEG; i += 256) {
        const float v = cnt_h[i];
        if (v != 0.0f) unsafeAtomicAdd(&cnt_g[i], v);
    }
}

__global__ __launch_bounds__(BLOCK) void accum_kernel(
        const int* __restrict__ sp, const float* __restrict__ feats,
        float* __restrict__ sum_g, float* __restrict__ sq_g) {
    // LDS layout [c][s] so bank = s%32 (random segs -> spread banks). 40 KB total.
    __shared__ float hist[CH_PER * S_SEG];   // 32 KB
    __shared__ float sq_h[S_SEG];            // 8 KB
    const int tid = threadIdx.x;
    const int chunk = blockIdx.x;
    const int grp = blockIdx.y;
    const int c0 = grp * CH_PER;

    for (int i = tid; i < CH_PER * S_SEG; i += BLOCK) hist[i] = 0.0f;
    for (int i = tid; i < S_SEG; i += BLOCK) sq_h[i] = 0.0f;
    __syncthreads();

    const int base = chunk * PIX_PER_BLOCK;
    const int4* sp4 = (const int4*)(sp + base);
    const int iters = PIX_PER_BLOCK / (BLOCK * 4);  // 8

    for (int it = 0; it < iters; ++it) {
        const int idx = it * BLOCK + tid;
        const int4 s4 = sp4[idx];
        float sq0 = 0.f, sq1 = 0.f, sq2 = 0.f, sq3 = 0.f;
#pragma unroll
        for (int c = 0; c < CH_PER; ++c) {
            const float4 v =
                ((const float4*)(feats + (size_t)(c0 + c) * P_PIX + base))[idx];
            atomicAdd(&hist[c * S_SEG + s4.x], v.x); sq0 = fmaf(v.x, v.x, sq0);
            atomicAdd(&hist[c * S_SEG + s4.y], v.y); sq1 = fmaf(v.y, v.y, sq1);
            atomicAdd(&hist[c * S_SEG + s4.z], v.z); sq2 = fmaf(v.z, v.z, sq2);
            atomicAdd(&hist[c * S_SEG + s4.w], v.w); sq3 = fmaf(v.w, v.w, sq3);
        }
        atomicAdd(&sq_h[s4.x], sq0);
        atomicAdd(&sq_h[s4.y], sq1);
        atomicAdd(&sq_h[s4.z], sq2);
        atomicAdd(&sq_h[s4.w], sq3);
    }
    __syncthreads();

    // flush LDS -> global (coalesced in s; hw fp32 atomic add, no return)
    for (int i = tid; i < CH_PER * S_SEG; i += BLOCK) {
        const int c = i >> 11, s = i & (S_SEG - 1);
        const float v = hist[i];
        if (v != 0.0f) unsafeAtomicAdd(&sum_g[(size_t)(c0 + c) * S_SEG + s], v);
    }
    for (int i = tid; i < S_SEG; i += BLOCK) {
        const float v = sq_h[i];
        if (v != 0.0f) unsafeAtomicAdd(&sq_g[i], v);
    }
}

__global__ void finalize_kernel(const float* __restrict__ sum_g,
                                const float* __restrict__ sq_g,
                                const float* __restrict__ cnt_g,
                                float* __restrict__ accum) {
    const int s = blockIdx.x * blockDim.x + threadIdx.x;  // 2048 threads
    const float cnt = cnt_g[s];
    const float n = fmaxf(cnt, 1.0f);
    float acc = 0.0f;
#pragma unroll 8
    for (int c = 0; c < C_ALL; ++c) {
        const float v = sum_g[c * S_SEG + s];  // coalesced in s
        acc = fmaf(v, v, acc);
    }
    const float var = sq_g[s] - acc / n;
    const float per = var / (64.0f * n);
    float loss = (cnt >= 2.0f) ? per : 0.0f;
    float cc = (cnt > 0.0f) ? 1.0f : 0.0f;
    for (int off = 32; off; off >>= 1) {
        loss += __shfl_down(loss, off);
        cc += __shfl_down(cc, off);
    }
    if ((threadIdx.x & 63) == 0) {
        unsafeAtomicAdd(&accum[0], loss);
        unsafeAtomicAdd(&accum[1], cc);
    }
}

__global__ void final_div(const float* __restrict__ accum, float* __restrict__ out) {
    out[0] = accum[0] / accum[1];
}

extern "C" void kernel_launch(void* const* d_in, const int* in_sizes, int n_in,
                              void* d_out, int out_size, void* d_ws, size_t ws_size,
                              hipStream_t stream) {
    const int* sp = (const int*)d_in[0];       // [2,1024,1024] int32, batch 0 only
    const float* feats = (const float*)d_in[1];// [2,64,1024,1024] fp32, batch 0 only
    float* ws = (float*)d_ws;
    float* sum_g = ws;
    float* sq_g = ws + OFF_SQ;
    float* cnt_g = ws + OFF_CNT;
    float* accum = ws + OFF_ACC;

    zero_kernel<<<(N_ZERO + 255) / 256, 256, 0, stream>>>(ws, N_ZERO);

    count_kernel<<<32, 256, 0, stream>>>(sp, cnt_g);

    dim3 grid(N_CHUNKS, N_GROUPS);
    accum_kernel<<<grid, BLOCK, 0, stream>>>(sp, feats, sum_g, sq_g);

    finalize_kernel<<<S_SEG / 256, 256, 0, stream>>>(sum_g, sq_g, cnt_g, accum);
    final_div<<<1, 1, 0, stream>>>(accum, (float*)d_out);
}

// Round 3
// 970.409 us; speedup vs baseline: 1.0307x; 1.0307x over previous
//
#include <hip/hip_runtime.h>

#define S_SEG 2048
#define C_ALL 64
#define P_PIX (1024 * 1024)
#define CH_PER 4        // channels per block
#define N_GROUPS 16     // 16 * 4 = 64 channels
#define N_CHUNKS 64     // pixel chunks
#define BLOCK 512
#define PIX_PER_BLOCK (P_PIX / N_CHUNKS)  // 16384

// ws layout (4-byte elems):
//   sum_g : [64][2048] float at 0        (131072)
//   sq_g  : [2048]     float at 131072
//   cnt_g : [2048]     int   at 133120
#define OFF_SQ   131072
#define OFF_CNT  133120
#define N_ZERO   135168

__global__ void zero_kernel(float* __restrict__ p, int n) {
    int i = blockIdx.x * blockDim.x + threadIdx.x;
    if (i < n) p[i] = 0.0f;  // bit pattern 0 also zeroes the int region
}

// counts: native int LDS atomics (ds_add_u32), 256 blocks
__global__ __launch_bounds__(256) void count_kernel(const int* __restrict__ sp,
                                                    int* __restrict__ cnt_g) {
    __shared__ int cnt_h[S_SEG];
    const int tid = threadIdx.x;
    for (int i = tid; i < S_SEG; i += 256) cnt_h[i] = 0;
    __syncthreads();
    const int base = blockIdx.x * (P_PIX / 256);  // 4096 px per block
    const int4* sp4 = (const int4*)(sp + base);
    const int iters = (P_PIX / 256) / (256 * 4);  // 4
    for (int it = 0; it < iters; ++it) {
        const int4 s4 = sp4[it * 256 + tid];
        atomicAdd(&cnt_h[s4.x], 1);
        atomicAdd(&cnt_h[s4.y], 1);
        atomicAdd(&cnt_h[s4.z], 1);
        atomicAdd(&cnt_h[s4.w], 1);
    }
    __syncthreads();
    for (int i = tid; i < S_SEG; i += 256) {
        const int v = cnt_h[i];
        if (v != 0) atomicAdd(&cnt_g[i], v);  // int global atomic: native
    }
}

__global__ __launch_bounds__(BLOCK) void accum_kernel(
        const int* __restrict__ sp, const float* __restrict__ feats,
        float* __restrict__ sum_g, float* __restrict__ sq_g) {
    // LDS layout [c][s] so bank = s%32 (random segs -> spread banks). 40 KB total.
    __shared__ float hist[CH_PER * S_SEG];   // 32 KB
    __shared__ float sq_h[S_SEG];            // 8 KB
    const int tid = threadIdx.x;
    const int chunk = blockIdx.x;
    const int grp = blockIdx.y;
    const int c0 = grp * CH_PER;

    for (int i = tid; i < CH_PER * S_SEG; i += BLOCK) hist[i] = 0.0f;
    for (int i = tid; i < S_SEG; i += BLOCK) sq_h[i] = 0.0f;
    __syncthreads();

    const int base = chunk * PIX_PER_BLOCK;
    const int4* sp4 = (const int4*)(sp + base);
    const int iters = PIX_PER_BLOCK / (BLOCK * 4);  // 8

    for (int it = 0; it < iters; ++it) {
        const int idx = it * BLOCK + tid;
        const int4 s4 = sp4[idx];
        float sq0 = 0.f, sq1 = 0.f, sq2 = 0.f, sq3 = 0.f;
#pragma unroll
        for (int c = 0; c < CH_PER; ++c) {
            const float4 v =
                ((const float4*)(feats + (size_t)(c0 + c) * P_PIX + base))[idx];
            // unsafeAtomicAdd -> native ds_add_f32 (default atomicAdd = CAS loop!)
            unsafeAtomicAdd(&hist[c * S_SEG + s4.x], v.x); sq0 = fmaf(v.x, v.x, sq0);
            unsafeAtomicAdd(&hist[c * S_SEG + s4.y], v.y); sq1 = fmaf(v.y, v.y, sq1);
            unsafeAtomicAdd(&hist[c * S_SEG + s4.z], v.z); sq2 = fmaf(v.z, v.z, sq2);
            unsafeAtomicAdd(&hist[c * S_SEG + s4.w], v.w); sq3 = fmaf(v.w, v.w, sq3);
        }
        unsafeAtomicAdd(&sq_h[s4.x], sq0);
        unsafeAtomicAdd(&sq_h[s4.y], sq1);
        unsafeAtomicAdd(&sq_h[s4.z], sq2);
        unsafeAtomicAdd(&sq_h[s4.w], sq3);
    }
    __syncthreads();

    // flush LDS -> global (coalesced in s; hw fp32 atomic add, no return)
    for (int i = tid; i < CH_PER * S_SEG; i += BLOCK) {
        const int c = i >> 11, s = i & (S_SEG - 1);
        const float v = hist[i];
        if (v != 0.0f) unsafeAtomicAdd(&sum_g[(size_t)(c0 + c) * S_SEG + s], v);
    }
    for (int i = tid; i < S_SEG; i += BLOCK) {
        const float v = sq_h[i];
        if (v != 0.0f) unsafeAtomicAdd(&sq_g[i], v);
    }
}

// single block: per-segment loss + full reduce + final divide
__global__ __launch_bounds__(1024) void finalize_kernel(
        const float* __restrict__ sum_g, const float* __restrict__ sq_g,
        const int* __restrict__ cnt_g, float* __restrict__ out) {
    __shared__ float red_l[16], red_c[16];
    const int tid = threadIdx.x;
    float loss = 0.0f, cc = 0.0f;
#pragma unroll
    for (int k = 0; k < 2; ++k) {
        const int s = tid + k * 1024;
        const float cnt = (float)cnt_g[s];
        const float n = fmaxf(cnt, 1.0f);
        float acc = 0.0f;
#pragma unroll 8
        for (int c = 0; c < C_ALL; ++c) {
            const float v = sum_g[c * S_SEG + s];  // coalesced in s
            acc = fmaf(v, v, acc);
        }
        const float var = sq_g[s] - acc / n;
        loss += (cnt >= 2.0f) ? var / (64.0f * n) : 0.0f;
        cc += (cnt > 0.0f) ? 1.0f : 0.0f;
    }
    for (int off = 32; off; off >>= 1) {
        loss += __shfl_down(loss, off);
        cc += __shfl_down(cc, off);
    }
    const int wave = tid >> 6;
    if ((tid & 63) == 0) { red_l[wave] = loss; red_c[wave] = cc; }
    __syncthreads();
    if (tid < 16) {
        loss = red_l[tid]; cc = red_c[tid];
        for (int off = 8; off; off >>= 1) {
            loss += __shfl_down(loss, off);
            cc += __shfl_down(cc, off);
        }
        if (tid == 0) out[0] = loss / cc;
    }
}

extern "C" void kernel_launch(void* const* d_in, const int* in_sizes, int n_in,
                              void* d_out, int out_size, void* d_ws, size_t ws_size,
                              hipStream_t stream) {
    const int* sp = (const int*)d_in[0];       // [2,1024,1024] int32, batch 0 only
    const float* feats = (const float*)d_in[1];// [2,64,1024,1024] fp32, batch 0 only
    float* ws = (float*)d_ws;
    float* sum_g = ws;
    float* sq_g = ws + OFF_SQ;
    int* cnt_g = (int*)(ws + OFF_CNT);

    zero_kernel<<<(N_ZERO + 255) / 256, 256, 0, stream>>>(ws, N_ZERO);

    count_kernel<<<256, 256, 0, stream>>>(sp, cnt_g);

    dim3 grid(N_CHUNKS, N_GROUPS);
    accum_kernel<<<grid, BLOCK, 0, stream>>>(sp, feats, sum_g, sq_g);

    finalize_kernel<<<1, 1024, 0, stream>>>(sum_g, sq_g, cnt_g, (float*)d_out);
}